// Round 3
// baseline (1061.502 us; speedup 1.0000x reference)
//
#include <hip/hip_runtime.h>

// ---------------------------------------------------------------------------
// 3-layer GraphSAGE forward, R5.
//   - x pre-converted to bf16 xb[1M][104] (208 MB < 256 MB L3) in a pass
//     merged with the edge histogram + weight prep. All gathers now bf16.
//   - sage_gemm: pair-unrolled register gather (2 edges' loads in flight),
//     self rows prefetched to regs, A staged via LDS (4x reuse), B fragments
//     read DIRECT from L2-resident Wt (zero intra-block reuse => no LDS stage,
//     no bank conflicts, 5 KB LDS/block).
// 7 dispatches total.
// ---------------------------------------------------------------------------

constexpr int kN1 = 262144;
constexpr int kN2 = 32768;
constexpr int kN3 = 8192;
constexpr int kE0 = 1310720;
constexpr int kE1 = 327680;
constexpr int kE2 = 81920;

constexpr int kXRows = 1000000;
constexpr int kXStride = 104;                      // bf16 cols, 16B-aligned rows
constexpr long long kCvtChunks = (long long)kXRows * 13;  // 13 uint4-chunks/row
constexpr int kCvtBlocks = (int)((kCvtChunks + 255) / 256);       // 50782
constexpr int kHistBlocks = (kE0 + kE1 + kE2) / 256;              // 6720
constexpr int kPrepBlocks = (65536 + 131072 + 131072) / 256;      // 1280

typedef __attribute__((ext_vector_type(8))) short short8;
typedef __attribute__((ext_vector_type(4))) float floatx4;

static inline unsigned cdiv_u(long long a, long long b) { return (unsigned)((a + b - 1) / b); }

__device__ __forceinline__ unsigned short f2bf(float f) {
  union { float f; unsigned u; } v; v.f = f;
  return (unsigned short)((v.u + 0x7fffu + ((v.u >> 16) & 1u)) >> 16);
}
__device__ __forceinline__ float blo(unsigned u) {
  union { unsigned u; float f; } v; v.u = u << 16; return v.f;
}
__device__ __forceinline__ float bhi(unsigned u) {
  union { unsigned u; float f; } v; v.u = u & 0xffff0000u; return v.f;
}
__device__ __forceinline__ void acc_bf8(float* g, uint4 v) {
  g[0] += blo(v.x); g[1] += bhi(v.x);
  g[2] += blo(v.y); g[3] += bhi(v.y);
  g[4] += blo(v.z); g[5] += bhi(v.z);
  g[6] += blo(v.w); g[7] += bhi(v.w);
}

// ---- weight prep helper: Wt[n][k] bf16, [Ws rows @ k<Kself | Wn @ KnOff..] ----
__device__ __forceinline__ void prep_one(
    const float* __restrict__ Ws, const float* __restrict__ Wn,
    unsigned short* __restrict__ Wt, int Kself, int KnOff, int Kneigh,
    int Ktot, int Nsrc, int t) {
  int n = t / Ktot, k = t - n * Ktot;
  float v = 0.f;
  if (n < Nsrc) {
    if (k < Kself) v = Ws[(size_t)k * Nsrc + n];
    else {
      int kk = k - KnOff;
      if (kk >= 0 && kk < Kneigh) v = Wn[(size_t)kk * Nsrc + n];
    }
  }
  Wt[(size_t)n * Ktot + k] = f2bf(v);
}

// ---- merged: x->bf16 convert | edge histograms | weight prep ----
// grid: [0,kCvtBlocks) cvt, [.., +kHistBlocks) hist, [.., +kPrepBlocks) prep.
__global__ __launch_bounds__(256) void cvt_hist_prep_kernel(
    const float* __restrict__ x, unsigned short* __restrict__ xb,
    const int* __restrict__ d0, int* __restrict__ c0,
    const int* __restrict__ d1, int* __restrict__ c1,
    const int* __restrict__ d2, int* __restrict__ c2,
    const float* __restrict__ Ws0, const float* __restrict__ Wn0, unsigned short* __restrict__ Wt0,
    const float* __restrict__ Ws1, const float* __restrict__ Wn1, unsigned short* __restrict__ Wt1,
    const float* __restrict__ Ws2, const float* __restrict__ Wn2, unsigned short* __restrict__ Wt2) {
  int b = blockIdx.x;
  if (b < kCvtBlocks) {
    long long t = (long long)b * 256 + threadIdx.x;
    if (t >= kCvtChunks) return;
    int r = (int)(t / 13), j = (int)(t - (long long)r * 13);
    const float* px = x + (size_t)r * 100 + j * 8;
    float4 a = *(const float4*)px;
    float4 b2 = make_float4(0.f, 0.f, 0.f, 0.f);
    if (j < 12) b2 = *(const float4*)(px + 4);
    uint4 pk;
    pk.x = (unsigned)f2bf(a.x) | ((unsigned)f2bf(a.y) << 16);
    pk.y = (unsigned)f2bf(a.z) | ((unsigned)f2bf(a.w) << 16);
    pk.z = (unsigned)f2bf(b2.x) | ((unsigned)f2bf(b2.y) << 16);
    pk.w = (unsigned)f2bf(b2.z) | ((unsigned)f2bf(b2.w) << 16);
    *(uint4*)(xb + (size_t)t * 8) = pk;  // xb offset t*8 == r*104 + j*8
  } else if (b < kCvtBlocks + kHistBlocks) {
    int e = (b - kCvtBlocks) * 256 + threadIdx.x;
    if (e < kE0) {
      atomicAdd(&c0[d0[e]], 1);
    } else if (e < kE0 + kE1) {
      atomicAdd(&c1[d1[e - kE0]], 1);
    } else {
      atomicAdd(&c2[d2[e - kE0 - kE1]], 1);
    }
  } else {
    int t = (b - kCvtBlocks - kHistBlocks) * 256 + threadIdx.x;
    if (t < 65536) prep_one(Ws0, Wn0, Wt0, 100, 128, 100, 256, 256, t);
    else if (t < 65536 + 131072) prep_one(Ws1, Wn1, Wt1, 256, 256, 256, 512, 256, t - 65536);
    else prep_one(Ws2, Wn2, Wt2, 256, 256, 256, 512, 47, t - 196608);
  }
}

// ---- merged exclusive-offset build (wave scan + global atomic base) ----
__global__ __launch_bounds__(256) void offsets3_kernel(
    const int* __restrict__ c0, int* __restrict__ o0, int* __restrict__ u0,
    const int* __restrict__ c1, int* __restrict__ o1, int* __restrict__ u1,
    const int* __restrict__ c2, int* __restrict__ o2, int* __restrict__ u2,
    int* __restrict__ gctr) {
  int i = blockIdx.x * 256 + threadIdx.x;  // grid covers exactly N1+N2+N3
  const int* cnt; int* off; int* cur; int* g; int local;
  if (i < kN1) {
    cnt = c0; off = o0; cur = u0; g = gctr + 0; local = i;
  } else if (i < kN1 + kN2) {
    cnt = c1; off = o1; cur = u1; g = gctr + 1; local = i - kN1;
  } else {
    cnt = c2; off = o2; cur = u2; g = gctr + 2; local = i - kN1 - kN2;
  }
  int lane = threadIdx.x & 63;
  int c = cnt[local];
  int v = c;
#pragma unroll
  for (int d = 1; d < 64; d <<= 1) {
    int u = __shfl_up(v, d);
    if (lane >= d) v += u;
  }
  int waveTotal = __shfl(v, 63);
  int base = 0;
  if (lane == 63) base = atomicAdd(g, waveTotal);
  base = __shfl(base, 63);
  int excl = base + v - c;
  off[local] = excl;
  cur[local] = excl;
}

// ---- merged CSR scatter ----
__global__ __launch_bounds__(256) void build3_kernel(
    const int* __restrict__ s0, const int* __restrict__ d0, int* __restrict__ u0, int* __restrict__ x0,
    const int* __restrict__ s1, const int* __restrict__ d1, int* __restrict__ u1, int* __restrict__ x1,
    const int* __restrict__ s2, const int* __restrict__ d2, int* __restrict__ u2, int* __restrict__ x2) {
  int e = blockIdx.x * 256 + threadIdx.x;
  const int *src, *dst; int *cur, *eidx; int le;
  if (e < kE0) {
    src = s0; dst = d0; cur = u0; eidx = x0; le = e;
  } else if (e < kE0 + kE1) {
    src = s1; dst = d1; cur = u1; eidx = x1; le = e - kE0;
  } else {
    src = s2; dst = d2; cur = u2; eidx = x2; le = e - kE0 - kE1;
  }
  int p = atomicAdd(&cur[dst[le]], 1);
  eidx[p] = src[le];
}

// ---------------------------------------------------------------------------
// Fused gather-mean + dual-source MFMA GEMM (all-bf16 source, stride SSTRIDE).
//   C[M,256] = act( [self | neigh_mean] @ Wt[256,KT]^T + b )
// Block 256 = 4 waves; BM=64, BN=256 (full N). Wave w: n in [w*64, w*64+64).
// Thread (r=tid>>2, cquad=tid&3) owns row r, cols {cquad*8 + 32*i}.
//   phase 0: prefetch self row slices to regs (selfheld).
//   phase 1: gather-mean, edge-pair unrolled: both edges' uint4 loads hoisted
//            => 2 row-loads in flight, half the latency stalls. L0's source is
//            the 208 MB L3-resident xb (~450cy) instead of 400 MB fp32 x.
//   phase 2: K-loop. A staged via LDS from regs only (no global between
//            barriers); B fragments DIRECT from Wt (L2-hot; each element used
//            by exactly one lane per block => LDS stage was pure overhead).
// ---------------------------------------------------------------------------
template <int KSELF, int KNEIGH, int SSTRIDE, bool RELU, bool OUT_BF16>
__global__ __launch_bounds__(256) void sage_gemm(
    const unsigned short* __restrict__ src,
    const int* __restrict__ off, const int* __restrict__ cnt,
    const int* __restrict__ eidx,
    const unsigned short* __restrict__ Wt,
    const float* __restrict__ bias, void* __restrict__ out, int nstore) {
  constexpr int KT = KSELF + KNEIGH;
  constexpr int NI = KNEIGH / 32;
  constexpr int NS = KSELF / 32;
  __shared__ __align__(16) unsigned short As[64 * 40];
  const int tid = threadIdx.x;
  const int lane = tid & 63, w = tid >> 6;
  const int q = lane >> 4, l15 = lane & 15;
  const size_t row0 = (size_t)blockIdx.x * 64;
  const int arow = tid >> 2, ac8 = (tid & 3) * 8;
  const size_t grow = row0 + arow;

  // ---- phase 0: prefetch self-row slices (issue before gather) ----
  uint4 selfheld[NS];
#pragma unroll
  for (int i = 0; i < NS; ++i) {
    int k = i * 32 + ac8;
    if (KSELF <= SSTRIDE || k < SSTRIDE)
      selfheld[i] = *(const uint4*)(src + grow * (size_t)SSTRIDE + k);
    else
      selfheld[i] = make_uint4(0, 0, 0, 0);
  }

  // ---- phase 1: gather-mean neigh half into registers (pair-unrolled) ----
  uint4 held[NI];
  {
    int o = off[grow], n = cnt[grow];
    float ga[NI * 8];
#pragma unroll
    for (int u = 0; u < NI * 8; ++u) ga[u] = 0.f;
    int e = 0;
    for (; e + 2 <= n; e += 2) {
      int s0 = eidx[o + e], s1 = eidx[o + e + 1];
      const unsigned short* p0 = src + (size_t)s0 * SSTRIDE + ac8;
      const unsigned short* p1 = src + (size_t)s1 * SSTRIDE + ac8;
      uint4 v0[NI], v1[NI];
#pragma unroll
      for (int i = 0; i < NI; ++i) {
        if (SSTRIDE >= KNEIGH || ac8 + 32 * i < SSTRIDE) {
          v0[i] = *(const uint4*)(p0 + 32 * i);
          v1[i] = *(const uint4*)(p1 + 32 * i);
        } else {
          v0[i] = make_uint4(0, 0, 0, 0);
          v1[i] = make_uint4(0, 0, 0, 0);
        }
      }
#pragma unroll
      for (int i = 0; i < NI; ++i) {
        acc_bf8(ga + i * 8, v0[i]);
        acc_bf8(ga + i * 8, v1[i]);
      }
    }
    if (e < n) {
      int s0 = eidx[o + e];
      const unsigned short* p0 = src + (size_t)s0 * SSTRIDE + ac8;
#pragma unroll
      for (int i = 0; i < NI; ++i) {
        if (SSTRIDE >= KNEIGH || ac8 + 32 * i < SSTRIDE) {
          uint4 v = *(const uint4*)(p0 + 32 * i);
          acc_bf8(ga + i * 8, v);
        }
      }
    }
    float inv = 1.0f / fmaxf((float)n, 1.0f);
#pragma unroll
    for (int i = 0; i < NI; ++i) {
      uint4 pk;
      pk.x = (unsigned)f2bf(ga[i * 8 + 0] * inv) | ((unsigned)f2bf(ga[i * 8 + 1] * inv) << 16);
      pk.y = (unsigned)f2bf(ga[i * 8 + 2] * inv) | ((unsigned)f2bf(ga[i * 8 + 3] * inv) << 16);
      pk.z = (unsigned)f2bf(ga[i * 8 + 4] * inv) | ((unsigned)f2bf(ga[i * 8 + 5] * inv) << 16);
      pk.w = (unsigned)f2bf(ga[i * 8 + 6] * inv) | ((unsigned)f2bf(ga[i * 8 + 7] * inv) << 16);
      held[i] = pk;
    }
  }

  // ---- phase 2: MFMA K-loop ----
  floatx4 acc[4][4];
#pragma unroll
  for (int i = 0; i < 4; ++i)
#pragma unroll
    for (int j = 0; j < 4; ++j) acc[i][j] = (floatx4){0.f, 0.f, 0.f, 0.f};

#pragma unroll
  for (int k0 = 0; k0 < KT; k0 += 32) {
    // B fragments direct from L2-resident Wt; independent of LDS barriers.
    short8 bfv[4];
#pragma unroll
    for (int j = 0; j < 4; ++j)
      bfv[j] = *(const short8*)&Wt[(size_t)(w * 64 + j * 16 + l15) * KT + k0 + q * 8];
    __syncthreads();
    uint4 pk = (k0 < KSELF) ? selfheld[k0 / 32] : held[(k0 - KSELF) / 32];
    *(uint4*)&As[arow * 40 + ac8] = pk;
    __syncthreads();
    short8 af[4];
#pragma unroll
    for (int i = 0; i < 4; ++i)
      af[i] = *(const short8*)&As[(i * 16 + l15) * 40 + q * 8];
#pragma unroll
    for (int i = 0; i < 4; ++i)
#pragma unroll
      for (int j = 0; j < 4; ++j)
        acc[i][j] = __builtin_amdgcn_mfma_f32_16x16x32_bf16(af[i], bfv[j], acc[i][j], 0, 0, 0);
  }

  float bj[4];
#pragma unroll
  for (int j = 0; j < 4; ++j) {
    int col = w * 64 + j * 16 + l15;
    bj[j] = (col < nstore) ? bias[col] : 0.f;
  }
#pragma unroll
  for (int i = 0; i < 4; ++i) {
#pragma unroll
    for (int reg = 0; reg < 4; ++reg) {
      size_t row = row0 + i * 16 + q * 4 + reg;
#pragma unroll
      for (int j = 0; j < 4; ++j) {
        int col = w * 64 + j * 16 + l15;
        float v = acc[i][j][reg] + bj[j];
        if (RELU) v = fmaxf(v, 0.f);
        if (OUT_BF16) {
          ((unsigned short*)out)[row * 256 + col] = f2bf(v);
        } else if (col < nstore) {
          ((float*)out)[row * (size_t)nstore + col] = v;
        }
      }
    }
  }
}

extern "C" void kernel_launch(void* const* d_in, const int* in_sizes, int n_in,
                              void* d_out, int out_size, void* d_ws, size_t ws_size,
                              hipStream_t stream) {
  const float* x   = (const float*)d_in[0];
  const int* es0   = (const int*)d_in[1];
  const int* ed0   = (const int*)d_in[2];
  const int* es1   = (const int*)d_in[3];
  const int* ed1   = (const int*)d_in[4];
  const int* es2   = (const int*)d_in[5];
  const int* ed2   = (const int*)d_in[6];
  const float* Ws0 = (const float*)d_in[7];
  const float* Wn0 = (const float*)d_in[8];
  const float* b0  = (const float*)d_in[9];
  const float* Ws1 = (const float*)d_in[10];
  const float* Wn1 = (const float*)d_in[11];
  const float* b1  = (const float*)d_in[12];
  const float* Ws2 = (const float*)d_in[13];
  const float* Wn2 = (const float*)d_in[14];
  const float* b2  = (const float*)d_in[15];
  float* out = (float*)d_out;

  // ---- workspace layout (disjoint, ~370 MB) ----
  char* ws = (char*)d_ws;
  unsigned short* h1b = (unsigned short*)(ws + 0ull);           // 134,217,728
  unsigned short* h2b = (unsigned short*)(ws + 134217728ull);   //  16,777,216
  unsigned short* xb  = (unsigned short*)(ws + 150994944ull);   // 208,000,128 (1M x 104 bf16 + pad)
  unsigned short* Wt0 = (unsigned short*)(ws + 358995072ull);   //     131,072
  unsigned short* Wt1 = (unsigned short*)(ws + 359126144ull);   //     262,144
  unsigned short* Wt2 = (unsigned short*)(ws + 359388288ull);   //     262,144
  int* cnt0 = (int*)(ws + 359650432ull);   // 1,048,576
  int* cnt1 = (int*)(ws + 360699008ull);   //   131,072
  int* cnt2 = (int*)(ws + 360830080ull);   //    32,768
  int* gctr = (int*)(ws + 360862848ull);   //       256
  int* off0 = (int*)(ws + 360863104ull);   // 1,048,576
  int* off1 = (int*)(ws + 361911680ull);   //   131,072
  int* off2 = (int*)(ws + 362042752ull);   //    32,768
  int* cur0 = (int*)(ws + 362075520ull);   // 1,048,576
  int* cur1 = (int*)(ws + 363124096ull);   //   131,072
  int* cur2 = (int*)(ws + 363255168ull);   //    32,768
  int* eidx0 = (int*)(ws + 363287936ull);  // 5,242,880
  int* eidx1 = (int*)(ws + 368530816ull);  // 1,310,720
  int* eidx2 = (int*)(ws + 369841536ull);  //   327,680

  // zero cnt0|cnt1|cnt2|gctr in one contiguous span [359650432, 360863104)
  hipMemsetAsync(ws + 359650432ull, 0, 1212672ull, stream);

  // ---- x->bf16 | histograms | weight prep (1 launch) ----
  cvt_hist_prep_kernel<<<kCvtBlocks + kHistBlocks + kPrepBlocks, 256, 0, stream>>>(
      x, xb, ed0, cnt0, ed1, cnt1, ed2, cnt2,
      Ws0, Wn0, Wt0, Ws1, Wn1, Wt1, Ws2, Wn2, Wt2);
  offsets3_kernel<<<cdiv_u(kN1 + kN2 + kN3, 256), 256, 0, stream>>>(
      cnt0, off0, cur0, cnt1, off1, cur1, cnt2, off2, cur2, gctr);
  build3_kernel<<<cdiv_u(kE0 + kE1 + kE2, 256), 256, 0, stream>>>(
      es0, ed0, cur0, eidx0, es1, ed1, cur1, eidx1, es2, ed2, cur2, eidx2);

  // ---- layer 0: fused gather+GEMM from L3-resident bf16 xb ----
  sage_gemm<128, 128, kXStride, true, true><<<kN1 / 64, 256, 0, stream>>>(
      xb, off0, cnt0, eidx0, Wt0, b0, h1b, 256);

  // ---- layer 1 ----
  sage_gemm<256, 256, 256, true, true><<<kN2 / 64, 256, 0, stream>>>(
      h1b, off1, cnt1, eidx1, Wt1, b1, h2b, 256);

  // ---- layer 2 ----
  sage_gemm<256, 256, 256, false, false><<<kN3 / 64, 256, 0, stream>>>(
      h2b, off2, cnt2, eidx2, Wt2, b2, out, 47);
}